// Round 7
// baseline (201.289 us; speedup 1.0000x reference)
//
#include <hip/hip_runtime.h>
#include <math.h>

#define PI_F 3.14159265358979323846f
#define BB 2
#define LL 1024
#define NCH 64
#define CHUNK 32
#define NCHUNK (LL/CHUNK)
#define NW 1408          // Wb rows: 512 Wv | 256 Wg1 | 16 Wk | 16 Wq | 96 pad0 | 512 Wo
#define YH 384           // Yh cols: 256 h | 16 kp | 16 qp | 96 pad

typedef __attribute__((ext_vector_type(8))) short short8;
typedef __attribute__((ext_vector_type(4))) float floatx4;
typedef __attribute__((ext_vector_type(2))) unsigned int uint2v;
typedef const __attribute__((address_space(1))) unsigned int cgu32;
typedef __attribute__((address_space(3))) unsigned int lu32;

__device__ __forceinline__ unsigned short f2bf(float f){
    unsigned u = __float_as_uint(f);
    unsigned r = (u + 0x7fff + ((u >> 16) & 1)) >> 16;   // RNE
    return (unsigned short)r;
}

// ---- prep: weights -> bf16 Wb[n][k], bcat; x -> bf16 xb ----
__global__ __launch_bounds__(128) void k_prep(
    const float* __restrict__ Wv, const float* __restrict__ Wg1,
    const float* __restrict__ Wk, const float* __restrict__ Wq,
    const float* __restrict__ Wo,
    const float* __restrict__ bv, const float* __restrict__ bg1,
    const float* __restrict__ bk, const float* __restrict__ bq,
    const float* __restrict__ bo, const float* __restrict__ x,
    unsigned short* __restrict__ Wb, float* __restrict__ bcat,
    unsigned short* __restrict__ xb)
{
    const int bid = blockIdx.x, tid = threadIdx.x;
    if (bid < NW){
        const int n = bid;
        const float* src = (n<512) ? Wv  + (size_t)n*512
                         : (n<768) ? Wg1 + (size_t)(n-512)*512
                         : (n<784) ? Wk  + (size_t)(n-768)*512
                         : (n<800) ? Wq  + (size_t)(n-784)*512
                         : (n<896) ? (const float*)0
                                   : Wo  + (size_t)(n-896)*512;
        float4 v = make_float4(0.f,0.f,0.f,0.f);
        if (src) v = ((const float4*)src)[tid];
        ushort4 o; o.x=f2bf(v.x); o.y=f2bf(v.y); o.z=f2bf(v.z); o.w=f2bf(v.w);
        ((ushort4*)(Wb + (size_t)n*512))[tid] = o;
        if (tid == 0)
            bcat[n] = (n<512)?bv[n] : (n<768)?bg1[n-512] : (n<784)?bk[n-768]
                    : (n<800)?bq[n-784] : (n<896)?0.f : bo[n-896];
    } else {
        const size_t i = (size_t)(bid - NW)*128 + tid;    // float4 index
        float4 v = ((const float4*)x)[i];
        ushort4 o; o.x=f2bf(v.x); o.y=f2bf(v.y); o.z=f2bf(v.z); o.w=f2bf(v.w);
        ((ushort4*)xb)[i] = o;
    }
}

// ---- MFMA 64x64x512 tile core (verified round 0) ----
__device__ __forceinline__ void gemm64x64(
    const unsigned short* Ag, const unsigned short* Bg,
    short* As, short* Bs, int tid, floatx4 acc[2][2])
{
    const int lane = tid & 63, w = tid >> 6;
    const int q = lane >> 4, m15 = lane & 15;
    for (int kt = 0; kt < 512; kt += 64) {
        __syncthreads();
        #pragma unroll
        for (int i = 0; i < 2; ++i) {
            const int rowbase = (w*2 + i) * 8;
            const int r  = rowbase + (lane >> 3);
            const int gb = (lane & 7) ^ (r & 7);
            const unsigned short* ga  = Ag + (size_t)r*512 + kt + gb*8;
            const unsigned short* gbp = Bg + (size_t)r*512 + kt + gb*8;
            __builtin_amdgcn_global_load_lds((cgu32*)(const void*)ga,
                                             (lu32*)(As + rowbase*64), 16, 0, 0);
            __builtin_amdgcn_global_load_lds((cgu32*)(const void*)gbp,
                                             (lu32*)(Bs + rowbase*64), 16, 0, 0);
        }
        __syncthreads();
        #pragma unroll
        for (int k32 = 0; k32 < 64; k32 += 32) {
            short8 af[2], bf[2];
            #pragma unroll
            for (int t = 0; t < 2; ++t) {
                const int ra  = 32*(w & 1) + 16*t + m15;
                const int sba = ((k32>>3) + q) ^ (ra & 7);
                af[t] = *(const short8*)(As + ra*64 + sba*8);
                const int rb  = 32*(w >> 1) + 16*t + m15;
                const int sbb = ((k32>>3) + q) ^ (rb & 7);
                bf[t] = *(const short8*)(Bs + rb*64 + sbb*8);
            }
            #pragma unroll
            for (int mt = 0; mt < 2; ++mt)
                #pragma unroll
                for (int nt = 0; nt < 2; ++nt)
                    acc[mt][nt] = __builtin_amdgcn_mfma_f32_16x16x32_bf16(
                        af[mt], bf[nt], acc[mt][nt], 0, 0, 0);
        }
    }
}

// ---- GEMM1: xb @ Wb[0:896]^T; n<512 -> Vt bf16 [b][d][l], n>=512 -> Yh fp32 ----
__global__ __launch_bounds__(256) void kg1(
    const unsigned short* __restrict__ xb, const unsigned short* __restrict__ Wb,
    const float* __restrict__ bcat, unsigned short* __restrict__ Vt,
    float* __restrict__ Yh)
{
    __shared__ short As[64*64], Bs[64*64];
    const int tid = threadIdx.x;
    const int row0 = blockIdx.x*64, n0 = blockIdx.y*64;
    floatx4 acc[2][2];
    #pragma unroll
    for (int mt=0;mt<2;++mt)
        #pragma unroll
        for (int nt=0;nt<2;++nt) acc[mt][nt] = (floatx4){0.f,0.f,0.f,0.f};
    gemm64x64(xb + (size_t)row0*512, Wb + (size_t)n0*512, As, Bs, tid, acc);
    const int lane = tid & 63, w = tid >> 6;
    const int wm = w & 1, wn = w >> 1, q = lane >> 4, m15 = lane & 15;
    if (n0 < 512){
        const int b = row0 >> 10, lb = row0 & 1023;
        #pragma unroll
        for (int mt=0;mt<2;++mt)
            #pragma unroll
            for (int nt=0;nt<2;++nt){
                const int d = n0 + 32*wn + 16*nt + m15;
                const float bb = bcat[d];
                const int l0 = lb + 32*wm + 16*mt + q*4;
                ushort4 o;
                o.x = f2bf(acc[mt][nt][0] + bb);
                o.y = f2bf(acc[mt][nt][1] + bb);
                o.z = f2bf(acc[mt][nt][2] + bb);
                o.w = f2bf(acc[mt][nt][3] + bb);
                *(ushort4*)(Vt + ((size_t)(b*512 + d))*1024 + l0) = o;
            }
    } else {
        #pragma unroll
        for (int mt=0;mt<2;++mt)
            #pragma unroll
            for (int nt=0;nt<2;++nt){
                const int n = n0 + 32*wn + 16*nt + m15;
                const float bb = bcat[n];
                #pragma unroll
                for (int reg=0;reg<4;++reg){
                    const int m = row0 + 32*wm + 16*mt + q*4 + reg;
                    Yh[(size_t)m*YH + (n-512)] = acc[mt][nt][reg] + bb;
                }
            }
    }
}

// ---- activations -> bf16 ab[l][64], Rb[l][64], aT[b][k][l] ----
__global__ __launch_bounds__(256) void k_act(
    const float* __restrict__ Yh, const float* __restrict__ Wg2,
    const float* __restrict__ bg2, const float* __restrict__ set_w,
    const float* __restrict__ pos_phases, const float* __restrict__ pos_weight,
    unsigned short* __restrict__ ab, unsigned short* __restrict__ Rb,
    unsigned short* __restrict__ aT)
{
    const int tid = threadIdx.x, lane = tid & 63, w = tid >> 6;
    const int row0 = blockIdx.x * 8;
    float s0=set_w[0], s1=set_w[1], s2=set_w[2], s3=set_w[3];
    float m = fmaxf(fmaxf(s0,s1), fmaxf(s2,s3));
    float e0=expf(s0-m), e1=expf(s1-m), e2=expf(s2-m), e3=expf(s3-m);
    float esum = e0+e1+e2+e3;
    float spw = 1.f/(1.f+expf(-pos_weight[0]));
    float b2 = bg2[0];
    #pragma unroll
    for (int rr=0;rr<2;++rr){
        int row = row0 + w + 4*rr;
        const float* yrow = Yh + (size_t)row*YH;
        float hs = 0.f;
        #pragma unroll
        for (int i=0;i<4;++i){
            float hv = yrow[lane + 64*i];
            float ge = 0.5f*hv*(1.f + erff(hv*0.70710678118f));
            hs += ge * Wg2[lane + 64*i];
        }
        #pragma unroll
        for (int off=32; off; off>>=1) hs += __shfl_xor(hs, off, 64);
        float g = 1.f/(1.f+expf(-(hs + b2)));
        if (lane < 16){
            int j = lane;
            int l = row & (LL-1);
            int b = row >> 10;
            float kang = PI_F*tanhf(yrow[256 + j]);
            float qang = PI_F*tanhf(yrow[272 + j]);
            float wsm = (j<4?e0: j<8?e1: j<12?e2: e3) / esum;
            float rnorm = 1.f/(2.f*sqrtf((float)(l+1)));
            float av[4], rv[4];
            av[0] = cosf(kang); av[1] = sinf(kang);
            float cw = g*wsm*rnorm;
            rv[0] = cw*cosf(qang); rv[1] = cw*sinf(qang);
            float ph = pos_phases[(size_t)l*16 + j];
            float pc = cosf(ph), ps = sinf(ph);
            av[2] = pc; av[3] = ps;
            float cp = (1.f-g)*spw*rnorm;
            rv[2] = cp*pc; rv[3] = cp*ps;
            unsigned short* arow = ab + (size_t)row*NCH;
            unsigned short* Rrow = Rb + (size_t)row*NCH;
            #pragma unroll
            for (int t=0;t<4;++t){
                arow[16*t + j] = f2bf(av[t]);
                Rrow[16*t + j] = f2bf(rv[t]);
                aT[((size_t)b*NCH + 16*t + j)*1024 + l] = f2bf(av[t]);
            }
        }
    }
}

// ---- k_scan: per-block (b, 64 d's) sequential scan over 32 chunks.
// S[ch][d] fp32 in regs; per chunk: T = tril(R@a^T)@V + R@bf16(S); S += a@V.
// Replaces k2a+k2b+k2c-scan with ZERO cross-block deps (no P/S0t).
__global__ __launch_bounds__(256) void k_scan(
    const unsigned short* __restrict__ ab, const unsigned short* __restrict__ Rb,
    const unsigned short* __restrict__ aT, const unsigned short* __restrict__ Vt,
    float* __restrict__ T)
{
    __shared__ short Msh[32*32];     // M chunk matrix, bf16
    __shared__ short Ssh[64*64];     // [d-local][ch] bf16, granule-swizzled
    const int b = blockIdx.y, d0 = blockIdx.x*64;
    const int tid = threadIdx.x, lane = tid & 63, w = tid >> 6;
    const int q = lane >> 4, m15 = lane & 15;
    const int dw = w*16 + m15;                 // d-local 0..63
    const int d  = d0 + dw;

    floatx4 S[4];                              // ch-tile mt: rows 16mt+q*4+reg, col d
    #pragma unroll
    for (int mt=0;mt<4;++mt) S[mt] = (floatx4){0.f,0.f,0.f,0.f};

    for (int c = 0; c < NCHUNK; ++c){
        const int grow = b*1024 + c*32;
        // ---- stage Ssh = bf16(S) (pre-update, exclusive prefix) ----
        #pragma unroll
        for (int mt=0;mt<4;++mt){
            unsigned p0 = (unsigned)f2bf(S[mt][0]) | ((unsigned)f2bf(S[mt][1])<<16);
            unsigned p1 = (unsigned)f2bf(S[mt][2]) | ((unsigned)f2bf(S[mt][3])<<16);
            const int gw = 2*mt + (q>>1);                       // ch granule
            const int adr = dw*64 + ((gw ^ (m15&7))<<3) + ((q&1)<<2);
            *(uint2v*)(Ssh + adr) = (uint2v){p0, p1};
        }
        if (w == 0){               // wave 0: M = tril(R_c @ a_c^T), bf16 -> Msh
            short8 ra[2][2], ba[2][2];
            #pragma unroll
            for (int ks=0;ks<2;++ks)
                #pragma unroll
                for (int t=0;t<2;++t){
                    ra[ks][t] = *(const short8*)(Rb + (size_t)(grow + 16*t + m15)*NCH + ks*32 + q*8);
                    ba[ks][t] = *(const short8*)(ab + (size_t)(grow + 16*t + m15)*NCH + ks*32 + q*8);
                }
            floatx4 mcc[2][2];
            #pragma unroll
            for (int mt=0;mt<2;++mt)
                #pragma unroll
                for (int nt=0;nt<2;++nt) mcc[mt][nt] = (floatx4){0.f,0.f,0.f,0.f};
            #pragma unroll
            for (int ks=0;ks<2;++ks)
                #pragma unroll
                for (int mt=0;mt<2;++mt)
                    #pragma unroll
                    for (int nt=0;nt<2;++nt)
                        mcc[mt][nt] = __builtin_amdgcn_mfma_f32_16x16x32_bf16(
                            ra[ks][mt], ba[ks][nt], mcc[mt][nt], 0,0,0);
            #pragma unroll
            for (int mt=0;mt<2;++mt)
                #pragma unroll
                for (int nt=0;nt<2;++nt){
                    const int nl = 16*nt + m15;
                    #pragma unroll
                    for (int reg=0;reg<4;++reg){
                        const int ml = 16*mt + q*4 + reg;
                        Msh[ml*32 + nl] = (nl <= ml) ? (short)f2bf(mcc[mt][nt][reg]) : (short)0;
                    }
                }
        }
        __syncthreads();

        // ---- fragments ----
        short8 a1[2];
        #pragma unroll
        for (int mt=0;mt<2;++mt)
            a1[mt] = *(const short8*)(Msh + (16*mt + m15)*32 + q*8);
        short8 s0[2];
        #pragma unroll
        for (int ks=0;ks<2;++ks){
            const int gr = 4*ks + q;
            s0[ks] = *(const short8*)(Ssh + dw*64 + ((gr ^ (m15&7))<<3));
        }
        short8 vf = *(const short8*)(Vt + ((size_t)(b*512 + d))*1024 + c*32 + q*8);
        short8 rA[2][2];
        #pragma unroll
        for (int ks=0;ks<2;++ks)
            #pragma unroll
            for (int mt=0;mt<2;++mt)
                rA[ks][mt] = *(const short8*)(Rb + (size_t)(grow + 16*mt + m15)*NCH + ks*32 + q*8);
        short8 aA[4];
        #pragma unroll
        for (int mt=0;mt<4;++mt)
            aA[mt] = *(const short8*)(aT + ((size_t)(b*NCH + 16*mt + m15))*1024 + c*32 + q*8);

        // ---- T chunk = M@V + R@S0 ----
        floatx4 t2[2];
        #pragma unroll
        for (int mt=0;mt<2;++mt){
            t2[mt] = (floatx4){0.f,0.f,0.f,0.f};
            t2[mt] = __builtin_amdgcn_mfma_f32_16x16x32_bf16(a1[mt],    vf,    t2[mt], 0,0,0);
            t2[mt] = __builtin_amdgcn_mfma_f32_16x16x32_bf16(rA[0][mt], s0[0], t2[mt], 0,0,0);
            t2[mt] = __builtin_amdgcn_mfma_f32_16x16x32_bf16(rA[1][mt], s0[1], t2[mt], 0,0,0);
        }
        // ---- S += a_c @ V_c ----
        #pragma unroll
        for (int mt=0;mt<4;++mt)
            S[mt] = __builtin_amdgcn_mfma_f32_16x16x32_bf16(aA[mt], vf, S[mt], 0,0,0);

        // ---- store T fp32 [row][d] ----
        #pragma unroll
        for (int mt=0;mt<2;++mt)
            #pragma unroll
            for (int reg=0;reg<4;++reg)
                T[(size_t)(grow + 16*mt + q*4 + reg)*512 + d] = t2[mt][reg];
        __syncthreads();   // protect Msh/Ssh before next chunk overwrites
    }
}

// ---- kg2ln: LN (stats from fp32 T) fused into GEMM2: out = x + LN(T)@Wo^T + bo
__global__ __launch_bounds__(256) void kg2ln(
    const float* __restrict__ T, const unsigned short* __restrict__ Wb,
    const float* __restrict__ bcat, const float* __restrict__ ln_g,
    const float* __restrict__ ln_b, const float* __restrict__ x,
    float* __restrict__ out)
{
    __shared__ short As[64*64], Bs[64*64];
    __shared__ float muL[64], rsL[64];
    const int tid = threadIdx.x, lane = tid & 63, w = tid >> 6;
    const int q = lane >> 4, m15 = lane & 15;
    const int row0 = blockIdx.x*64, n0 = blockIdx.y*64;

    // LN stats: wave w handles rows w*16 .. w*16+15
    for (int i=0;i<16;++i){
        const int r = w*16 + i;
        const float* tr = T + (size_t)(row0 + r)*512;
        float s=0.f, sq=0.f;
        #pragma unroll
        for (int t=0;t<8;++t){
            float v = tr[lane + 64*t];
            s += v; sq += v*v;
        }
        #pragma unroll
        for (int off=32; off; off>>=1){
            s += __shfl_xor(s, off, 64); sq += __shfl_xor(sq, off, 64);
        }
        if (lane == 0){
            float mu = s*(1.f/512.f);
            float var = sq*(1.f/512.f) - mu*mu;
            muL[r] = mu; rsL[r] = rsqrtf(var + 1e-5f);
        }
    }
    __syncthreads();

    floatx4 acc[2][2];
    #pragma unroll
    for (int mt=0;mt<2;++mt)
        #pragma unroll
        for (int nt=0;nt<2;++nt) acc[mt][nt] = (floatx4){0.f,0.f,0.f,0.f};

    const unsigned short* Bg = Wb + (size_t)(896 + n0)*512;
    for (int kt = 0; kt < 512; kt += 64) {
        __syncthreads();
        short8 av[2];
        #pragma unroll
        for (int i = 0; i < 2; ++i) {
            const int rowbase = (w*2 + i) * 8;
            const int r  = rowbase + (lane >> 3);
            const int gb = (lane & 7) ^ (r & 7);
            __builtin_amdgcn_global_load_lds(
                (cgu32*)(const void*)(Bg + (size_t)r*512 + kt + gb*8),
                (lu32*)(Bs + rowbase*64), 16, 0, 0);
            // A-side: load 8 fp32 from T, normalize, convert
            const float* tp = T + (size_t)(row0 + r)*512 + kt + gb*8;
            float4 t0 = *(const float4*)tp;
            float4 t1 = *(const float4*)(tp + 4);
            const float* gp = ln_g + kt + gb*8;
            const float* bp = ln_b + kt + gb*8;
            float4 g0 = *(const float4*)gp, g1 = *(const float4*)(gp + 4);
            float4 b0 = *(const float4*)bp, b1 = *(const float4*)(bp + 4);
            const float mu = muL[r], rs = rsL[r];
            short8 o;
            o[0] = (short)f2bf((t0.x - mu)*rs*g0.x + b0.x);
            o[1] = (short)f2bf((t0.y - mu)*rs*g0.y + b0.y);
            o[2] = (short)f2bf((t0.z - mu)*rs*g0.z + b0.z);
            o[3] = (short)f2bf((t0.w - mu)*rs*g0.w + b0.w);
            o[4] = (short)f2bf((t1.x - mu)*rs*g1.x + b1.x);
            o[5] = (short)f2bf((t1.y - mu)*rs*g1.y + b1.y);
            o[6] = (short)f2bf((t1.z - mu)*rs*g1.z + b1.z);
            o[7] = (short)f2bf((t1.w - mu)*rs*g1.w + b1.w);
            av[i] = o;
        }
        #pragma unroll
        for (int i = 0; i < 2; ++i)
            *(short8*)(As + ((w*2 + i)*8)*64 + lane*8) = av[i];
        __syncthreads();
        #pragma unroll
        for (int k32 = 0; k32 < 64; k32 += 32) {
            short8 af[2], bf[2];
            #pragma unroll
            for (int t = 0; t < 2; ++t) {
                const int ra  = 32*(w & 1) + 16*t + m15;
                const int sba = ((k32>>3) + q) ^ (ra & 7);
                af[t] = *(const short8*)(As + ra*64 + sba*8);
                const int rb  = 32*(w >> 1) + 16*t + m15;
                const int sbb = ((k32>>3) + q) ^ (rb & 7);
                bf[t] = *(const short8*)(Bs + rb*64 + sbb*8);
            }
            #pragma unroll
            for (int mt = 0; mt < 2; ++mt)
                #pragma unroll
                for (int nt = 0; nt < 2; ++nt)
                    acc[mt][nt] = __builtin_amdgcn_mfma_f32_16x16x32_bf16(
                        af[mt], bf[nt], acc[mt][nt], 0, 0, 0);
        }
    }
    const int wm = w & 1, wn = w >> 1;
    #pragma unroll
    for (int mt=0;mt<2;++mt)
        #pragma unroll
        for (int nt=0;nt<2;++nt){
            const int n = n0 + 32*wn + 16*nt + m15;
            const float bb = bcat[896 + n];
            #pragma unroll
            for (int reg=0;reg<4;++reg){
                const int m = row0 + 32*wm + 16*mt + q*4 + reg;
                out[(size_t)m*512 + n] = x[(size_t)m*512 + n] + acc[mt][nt][reg] + bb;
            }
        }
}

extern "C" void kernel_launch(void* const* d_in, const int* in_sizes, int n_in,
                              void* d_out, int out_size, void* d_ws, size_t ws_size,
                              hipStream_t stream) {
    const float* x    = (const float*)d_in[0];
    const float* Wk   = (const float*)d_in[1];
    const float* bk   = (const float*)d_in[2];
    const float* Wq   = (const float*)d_in[3];
    const float* bq   = (const float*)d_in[4];
    const float* Wv   = (const float*)d_in[5];
    const float* bv   = (const float*)d_in[6];
    const float* ln_g = (const float*)d_in[7];
    const float* ln_b = (const float*)d_in[8];
    const float* Wo   = (const float*)d_in[9];
    const float* bo   = (const float*)d_in[10];
    const float* set_w      = (const float*)d_in[11];
    const float* pos_phases = (const float*)d_in[12];
    const float* pos_weight = (const float*)d_in[13];
    const float* Wg1  = (const float*)d_in[14];
    const float* bg1  = (const float*)d_in[15];
    const float* Wg2  = (const float*)d_in[16];
    const float* bg2  = (const float*)d_in[17];
    float* out = (float*)d_out;

    // workspace: fp32 region, then bf16 region (~14 MB)
    float* ws   = (float*)d_ws;
    float* Yh   = ws;                                     // 2048*384
    float* T    = Yh + (size_t)2048*YH;                   // 2048*512 fp32
    float* bcat = T  + (size_t)2048*512;                  // 1408
    unsigned short* Wb  = (unsigned short*)(bcat + NW);   // 1408*512
    unsigned short* xb  = Wb  + (size_t)NW*512;           // 2048*512
    unsigned short* Vt  = xb  + (size_t)2048*512;         // 2*512*1024
    unsigned short* ab  = Vt  + (size_t)BB*512*1024;      // 2048*64
    unsigned short* Rb  = ab  + (size_t)2048*NCH;         // 2048*64
    unsigned short* aT  = Rb  + (size_t)2048*NCH;         // 2*64*1024

    k_prep<<<dim3(NW + 2048), 128, 0, stream>>>(
        Wv,Wg1,Wk,Wq,Wo, bv,bg1,bk,bq,bo, x, Wb, bcat, xb);
    kg1<<<dim3(2048/64, 14), 256, 0, stream>>>(xb, Wb, bcat, Vt, Yh);
    k_act<<<dim3(2048/8), 256, 0, stream>>>(
        Yh, Wg2, bg2, set_w, pos_phases, pos_weight, ab, Rb, aT);
    k_scan<<<dim3(8, BB), 256, 0, stream>>>(ab, Rb, aT, Vt, T);
    kg2ln<<<dim3(2048/64, 512/64), 256, 0, stream>>>(
        T, Wb, bcat, ln_g, ln_b, x, out);
}

// Round 8
// 156.356 us; speedup vs baseline: 1.2874x; 1.2874x over previous
//
#include <hip/hip_runtime.h>
#include <math.h>

#define PI_F 3.14159265358979323846f
#define BB 2
#define LL 1024
#define NCH 64
#define CHUNK 32
#define NCHUNK (LL/CHUNK)
#define NW 1408          // Wb rows: 512 Wv | 256 Wg1 | 16 Wk | 16 Wq | 96 pad0 | 512 Wo
#define YH 384           // Yh cols: 256 h | 16 kp | 16 qp | 96 pad

typedef __attribute__((ext_vector_type(8))) short short8;
typedef __attribute__((ext_vector_type(4))) float floatx4;
typedef __attribute__((ext_vector_type(2))) unsigned int uint2v;
typedef const __attribute__((address_space(1))) unsigned int cgu32;
typedef __attribute__((address_space(3))) unsigned int lu32;

__device__ __forceinline__ unsigned short f2bf(float f){
    unsigned u = __float_as_uint(f);
    unsigned r = (u + 0x7fff + ((u >> 16) & 1)) >> 16;   // RNE
    return (unsigned short)r;
}

// ---- prep: weights -> bf16 Wb[n][k], bcat; x -> bf16 xb ----
__global__ __launch_bounds__(128) void k_prep(
    const float* __restrict__ Wv, const float* __restrict__ Wg1,
    const float* __restrict__ Wk, const float* __restrict__ Wq,
    const float* __restrict__ Wo,
    const float* __restrict__ bv, const float* __restrict__ bg1,
    const float* __restrict__ bk, const float* __restrict__ bq,
    const float* __restrict__ bo, const float* __restrict__ x,
    unsigned short* __restrict__ Wb, float* __restrict__ bcat,
    unsigned short* __restrict__ xb)
{
    const int bid = blockIdx.x, tid = threadIdx.x;
    if (bid < NW){
        const int n = bid;
        const float* src = (n<512) ? Wv  + (size_t)n*512
                         : (n<768) ? Wg1 + (size_t)(n-512)*512
                         : (n<784) ? Wk  + (size_t)(n-768)*512
                         : (n<800) ? Wq  + (size_t)(n-784)*512
                         : (n<896) ? (const float*)0
                                   : Wo  + (size_t)(n-896)*512;
        float4 v = make_float4(0.f,0.f,0.f,0.f);
        if (src) v = ((const float4*)src)[tid];
        ushort4 o; o.x=f2bf(v.x); o.y=f2bf(v.y); o.z=f2bf(v.z); o.w=f2bf(v.w);
        ((ushort4*)(Wb + (size_t)n*512))[tid] = o;
        if (tid == 0)
            bcat[n] = (n<512)?bv[n] : (n<768)?bg1[n-512] : (n<784)?bk[n-768]
                    : (n<800)?bq[n-784] : (n<896)?0.f : bo[n-896];
    } else {
        const size_t i = (size_t)(bid - NW)*128 + tid;    // float4 index
        float4 v = ((const float4*)x)[i];
        ushort4 o; o.x=f2bf(v.x); o.y=f2bf(v.y); o.z=f2bf(v.z); o.w=f2bf(v.w);
        ((ushort4*)xb)[i] = o;
    }
}

// ---- MFMA 64x64x512 tile core (verified round 0) ----
__device__ __forceinline__ void gemm64x64(
    const unsigned short* Ag, const unsigned short* Bg,
    short* As, short* Bs, int tid, floatx4 acc[2][2])
{
    const int lane = tid & 63, w = tid >> 6;
    const int q = lane >> 4, m15 = lane & 15;
    for (int kt = 0; kt < 512; kt += 64) {
        __syncthreads();
        #pragma unroll
        for (int i = 0; i < 2; ++i) {
            const int rowbase = (w*2 + i) * 8;
            const int r  = rowbase + (lane >> 3);
            const int gb = (lane & 7) ^ (r & 7);
            const unsigned short* ga  = Ag + (size_t)r*512 + kt + gb*8;
            const unsigned short* gbp = Bg + (size_t)r*512 + kt + gb*8;
            __builtin_amdgcn_global_load_lds((cgu32*)(const void*)ga,
                                             (lu32*)(As + rowbase*64), 16, 0, 0);
            __builtin_amdgcn_global_load_lds((cgu32*)(const void*)gbp,
                                             (lu32*)(Bs + rowbase*64), 16, 0, 0);
        }
        __syncthreads();
        #pragma unroll
        for (int k32 = 0; k32 < 64; k32 += 32) {
            short8 af[2], bf[2];
            #pragma unroll
            for (int t = 0; t < 2; ++t) {
                const int ra  = 32*(w & 1) + 16*t + m15;
                const int sba = ((k32>>3) + q) ^ (ra & 7);
                af[t] = *(const short8*)(As + ra*64 + sba*8);
                const int rb  = 32*(w >> 1) + 16*t + m15;
                const int sbb = ((k32>>3) + q) ^ (rb & 7);
                bf[t] = *(const short8*)(Bs + rb*64 + sbb*8);
            }
            #pragma unroll
            for (int mt = 0; mt < 2; ++mt)
                #pragma unroll
                for (int nt = 0; nt < 2; ++nt)
                    acc[mt][nt] = __builtin_amdgcn_mfma_f32_16x16x32_bf16(
                        af[mt], bf[nt], acc[mt][nt], 0, 0, 0);
        }
    }
}

// ---- GEMM1: xb @ Wb[0:896]^T; n<512 -> Vt bf16 [b][d][l], n>=512 -> Yh fp32 ----
__global__ __launch_bounds__(256) void kg1(
    const unsigned short* __restrict__ xb, const unsigned short* __restrict__ Wb,
    const float* __restrict__ bcat, unsigned short* __restrict__ Vt,
    float* __restrict__ Yh)
{
    __shared__ short As[64*64], Bs[64*64];
    const int tid = threadIdx.x;
    const int row0 = blockIdx.x*64, n0 = blockIdx.y*64;
    floatx4 acc[2][2];
    #pragma unroll
    for (int mt=0;mt<2;++mt)
        #pragma unroll
        for (int nt=0;nt<2;++nt) acc[mt][nt] = (floatx4){0.f,0.f,0.f,0.f};
    gemm64x64(xb + (size_t)row0*512, Wb + (size_t)n0*512, As, Bs, tid, acc);
    const int lane = tid & 63, w = tid >> 6;
    const int wm = w & 1, wn = w >> 1, q = lane >> 4, m15 = lane & 15;
    if (n0 < 512){
        const int b = row0 >> 10, lb = row0 & 1023;
        #pragma unroll
        for (int mt=0;mt<2;++mt)
            #pragma unroll
            for (int nt=0;nt<2;++nt){
                const int d = n0 + 32*wn + 16*nt + m15;
                const float bb = bcat[d];
                const int l0 = lb + 32*wm + 16*mt + q*4;
                ushort4 o;
                o.x = f2bf(acc[mt][nt][0] + bb);
                o.y = f2bf(acc[mt][nt][1] + bb);
                o.z = f2bf(acc[mt][nt][2] + bb);
                o.w = f2bf(acc[mt][nt][3] + bb);
                *(ushort4*)(Vt + ((size_t)(b*512 + d))*1024 + l0) = o;
            }
    } else {
        #pragma unroll
        for (int mt=0;mt<2;++mt)
            #pragma unroll
            for (int nt=0;nt<2;++nt){
                const int n = n0 + 32*wn + 16*nt + m15;
                const float bb = bcat[n];
                #pragma unroll
                for (int reg=0;reg<4;++reg){
                    const int m = row0 + 32*wm + 16*mt + q*4 + reg;
                    Yh[(size_t)m*YH + (n-512)] = acc[mt][nt][reg] + bb;
                }
            }
    }
}

// ---- activations -> bf16 ab[l][64], Rb[l][64], aT[b][k][l] ----
__global__ __launch_bounds__(256) void k_act(
    const float* __restrict__ Yh, const float* __restrict__ Wg2,
    const float* __restrict__ bg2, const float* __restrict__ set_w,
    const float* __restrict__ pos_phases, const float* __restrict__ pos_weight,
    unsigned short* __restrict__ ab, unsigned short* __restrict__ Rb,
    unsigned short* __restrict__ aT)
{
    const int tid = threadIdx.x, lane = tid & 63, w = tid >> 6;
    const int row0 = blockIdx.x * 8;
    float s0=set_w[0], s1=set_w[1], s2=set_w[2], s3=set_w[3];
    float m = fmaxf(fmaxf(s0,s1), fmaxf(s2,s3));
    float e0=expf(s0-m), e1=expf(s1-m), e2=expf(s2-m), e3=expf(s3-m);
    float esum = e0+e1+e2+e3;
    float spw = 1.f/(1.f+expf(-pos_weight[0]));
    float b2 = bg2[0];
    #pragma unroll
    for (int rr=0;rr<2;++rr){
        int row = row0 + w + 4*rr;
        const float* yrow = Yh + (size_t)row*YH;
        float hs = 0.f;
        #pragma unroll
        for (int i=0;i<4;++i){
            float hv = yrow[lane + 64*i];
            float ge = 0.5f*hv*(1.f + erff(hv*0.70710678118f));
            hs += ge * Wg2[lane + 64*i];
        }
        #pragma unroll
        for (int off=32; off; off>>=1) hs += __shfl_xor(hs, off, 64);
        float g = 1.f/(1.f+expf(-(hs + b2)));
        if (lane < 16){
            int j = lane;
            int l = row & (LL-1);
            int b = row >> 10;
            float kang = PI_F*tanhf(yrow[256 + j]);
            float qang = PI_F*tanhf(yrow[272 + j]);
            float wsm = (j<4?e0: j<8?e1: j<12?e2: e3) / esum;
            float rnorm = 1.f/(2.f*sqrtf((float)(l+1)));
            float av[4], rv[4];
            av[0] = cosf(kang); av[1] = sinf(kang);
            float cw = g*wsm*rnorm;
            rv[0] = cw*cosf(qang); rv[1] = cw*sinf(qang);
            float ph = pos_phases[(size_t)l*16 + j];
            float pc = cosf(ph), ps = sinf(ph);
            av[2] = pc; av[3] = ps;
            float cp = (1.f-g)*spw*rnorm;
            rv[2] = cp*pc; rv[3] = cp*ps;
            unsigned short* arow = ab + (size_t)row*NCH;
            unsigned short* Rrow = Rb + (size_t)row*NCH;
            #pragma unroll
            for (int t=0;t<4;++t){
                arow[16*t + j] = f2bf(av[t]);
                Rrow[16*t + j] = f2bf(rv[t]);
                aT[((size_t)b*NCH + 16*t + j)*1024 + l] = f2bf(av[t]);
            }
        }
    }
}

// ---- k_scan: one block per (d-group, b, chunk). Redundant prefix replay:
// S = sum_{c'<c} a_c'^T @ V_c' rebuilt in-regs (4 MFMA + 5 loads per chunk,
// no barriers, pipelined), then round-7's verified single-chunk body:
// T_c = tril(R@a^T)@V + R@bf16(S). 512 blocks, zero cross-block deps.
__global__ __launch_bounds__(256) void k_scan(
    const unsigned short* __restrict__ ab, const unsigned short* __restrict__ Rb,
    const unsigned short* __restrict__ aT, const unsigned short* __restrict__ Vt,
    float* __restrict__ T)
{
    __shared__ short Msh[32*32];     // M chunk matrix, bf16
    __shared__ short Ssh[64*64];     // [d-local][ch] bf16, granule-swizzled
    const int d0 = blockIdx.x*64, b = blockIdx.y, c = blockIdx.z;
    const int tid = threadIdx.x, lane = tid & 63, w = tid >> 6;
    const int q = lane >> 4, m15 = lane & 15;
    const int dw = w*16 + m15;                 // d-local 0..63
    const int d  = d0 + dw;
    const int grow = b*1024 + c*32;

    // ---- prefix replay: S = sum over chunks < c ----
    floatx4 S[4];
    #pragma unroll
    for (int mt=0;mt<4;++mt) S[mt] = (floatx4){0.f,0.f,0.f,0.f};
    const unsigned short* vrow = Vt + ((size_t)(b*512 + d))*1024;
    for (int c2 = 0; c2 < c; ++c2){
        short8 vf2 = *(const short8*)(vrow + c2*32 + q*8);
        #pragma unroll
        for (int mt=0;mt<4;++mt){
            short8 aA2 = *(const short8*)(aT + ((size_t)(b*NCH + 16*mt + m15))*1024 + c2*32 + q*8);
            S[mt] = __builtin_amdgcn_mfma_f32_16x16x32_bf16(aA2, vf2, S[mt], 0,0,0);
        }
    }

    // ---- stage Ssh = bf16(S) (exclusive prefix for this chunk) ----
    #pragma unroll
    for (int mt=0;mt<4;++mt){
        unsigned p0 = (unsigned)f2bf(S[mt][0]) | ((unsigned)f2bf(S[mt][1])<<16);
        unsigned p1 = (unsigned)f2bf(S[mt][2]) | ((unsigned)f2bf(S[mt][3])<<16);
        const int gw = 2*mt + (q>>1);                       // ch granule
        const int adr = dw*64 + ((gw ^ (m15&7))<<3) + ((q&1)<<2);
        *(uint2v*)(Ssh + adr) = (uint2v){p0, p1};
    }
    if (w == 0){               // wave 0: M = tril(R_c @ a_c^T), bf16 -> Msh
        short8 ra[2][2], ba[2][2];
        #pragma unroll
        for (int ks=0;ks<2;++ks)
            #pragma unroll
            for (int t=0;t<2;++t){
                ra[ks][t] = *(const short8*)(Rb + (size_t)(grow + 16*t + m15)*NCH + ks*32 + q*8);
                ba[ks][t] = *(const short8*)(ab + (size_t)(grow + 16*t + m15)*NCH + ks*32 + q*8);
            }
        floatx4 mcc[2][2];
        #pragma unroll
        for (int mt=0;mt<2;++mt)
            #pragma unroll
            for (int nt=0;nt<2;++nt) mcc[mt][nt] = (floatx4){0.f,0.f,0.f,0.f};
        #pragma unroll
        for (int ks=0;ks<2;++ks)
            #pragma unroll
            for (int mt=0;mt<2;++mt)
                #pragma unroll
                for (int nt=0;nt<2;++nt)
                    mcc[mt][nt] = __builtin_amdgcn_mfma_f32_16x16x32_bf16(
                        ra[ks][mt], ba[ks][nt], mcc[mt][nt], 0,0,0);
        #pragma unroll
        for (int mt=0;mt<2;++mt)
            #pragma unroll
            for (int nt=0;nt<2;++nt){
                const int nl = 16*nt + m15;
                #pragma unroll
                for (int reg=0;reg<4;++reg){
                    const int ml = 16*mt + q*4 + reg;
                    Msh[ml*32 + nl] = (nl <= ml) ? (short)f2bf(mcc[mt][nt][reg]) : (short)0;
                }
            }
    }
    __syncthreads();

    // ---- fragments ----
    short8 a1[2];
    #pragma unroll
    for (int mt=0;mt<2;++mt)
        a1[mt] = *(const short8*)(Msh + (16*mt + m15)*32 + q*8);
    short8 s0[2];
    #pragma unroll
    for (int ks=0;ks<2;++ks){
        const int gr = 4*ks + q;
        s0[ks] = *(const short8*)(Ssh + dw*64 + ((gr ^ (m15&7))<<3));
    }
    short8 vf = *(const short8*)(vrow + c*32 + q*8);
    short8 rA[2][2];
    #pragma unroll
    for (int ks=0;ks<2;++ks)
        #pragma unroll
        for (int mt=0;mt<2;++mt)
            rA[ks][mt] = *(const short8*)(Rb + (size_t)(grow + 16*mt + m15)*NCH + ks*32 + q*8);

    // ---- T chunk = M@V + R@S0 ----
    floatx4 t2[2];
    #pragma unroll
    for (int mt=0;mt<2;++mt){
        t2[mt] = (floatx4){0.f,0.f,0.f,0.f};
        t2[mt] = __builtin_amdgcn_mfma_f32_16x16x32_bf16(a1[mt],    vf,    t2[mt], 0,0,0);
        t2[mt] = __builtin_amdgcn_mfma_f32_16x16x32_bf16(rA[0][mt], s0[0], t2[mt], 0,0,0);
        t2[mt] = __builtin_amdgcn_mfma_f32_16x16x32_bf16(rA[1][mt], s0[1], t2[mt], 0,0,0);
    }

    // ---- store T fp32 [row][d] ----
    #pragma unroll
    for (int mt=0;mt<2;++mt)
        #pragma unroll
        for (int reg=0;reg<4;++reg)
            T[(size_t)(grow + 16*mt + q*4 + reg)*512 + d] = t2[mt][reg];
}

// ---- kg2ln: LN (stats from fp32 T) fused into GEMM2: out = x + LN(T)@Wo^T + bo
__global__ __launch_bounds__(256) void kg2ln(
    const float* __restrict__ T, const unsigned short* __restrict__ Wb,
    const float* __restrict__ bcat, const float* __restrict__ ln_g,
    const float* __restrict__ ln_b, const float* __restrict__ x,
    float* __restrict__ out)
{
    __shared__ short As[64*64], Bs[64*64];
    __shared__ float muL[64], rsL[64];
    const int tid = threadIdx.x, lane = tid & 63, w = tid >> 6;
    const int q = lane >> 4, m15 = lane & 15;
    const int row0 = blockIdx.x*64, n0 = blockIdx.y*64;

    // LN stats: wave w handles rows w*16 .. w*16+15
    for (int i=0;i<16;++i){
        const int r = w*16 + i;
        const float* tr = T + (size_t)(row0 + r)*512;
        float s=0.f, sq=0.f;
        #pragma unroll
        for (int t=0;t<8;++t){
            float v = tr[lane + 64*t];
            s += v; sq += v*v;
        }
        #pragma unroll
        for (int off=32; off; off>>=1){
            s += __shfl_xor(s, off, 64); sq += __shfl_xor(sq, off, 64);
        }
        if (lane == 0){
            float mu = s*(1.f/512.f);
            float var = sq*(1.f/512.f) - mu*mu;
            muL[r] = mu; rsL[r] = rsqrtf(var + 1e-5f);
        }
    }
    __syncthreads();

    floatx4 acc[2][2];
    #pragma unroll
    for (int mt=0;mt<2;++mt)
        #pragma unroll
        for (int nt=0;nt<2;++nt) acc[mt][nt] = (floatx4){0.f,0.f,0.f,0.f};

    const unsigned short* Bg = Wb + (size_t)(896 + n0)*512;
    for (int kt = 0; kt < 512; kt += 64) {
        __syncthreads();
        short8 av[2];
        #pragma unroll
        for (int i = 0; i < 2; ++i) {
            const int rowbase = (w*2 + i) * 8;
            const int r  = rowbase + (lane >> 3);
            const int gb = (lane & 7) ^ (r & 7);
            __builtin_amdgcn_global_load_lds(
                (cgu32*)(const void*)(Bg + (size_t)r*512 + kt + gb*8),
                (lu32*)(Bs + rowbase*64), 16, 0, 0);
            // A-side: load 8 fp32 from T, normalize, convert
            const float* tp = T + (size_t)(row0 + r)*512 + kt + gb*8;
            float4 t0 = *(const float4*)tp;
            float4 t1 = *(const float4*)(tp + 4);
            const float* gp = ln_g + kt + gb*8;
            const float* bp = ln_b + kt + gb*8;
            float4 g0 = *(const float4*)gp, g1 = *(const float4*)(gp + 4);
            float4 b0 = *(const float4*)bp, b1 = *(const float4*)(bp + 4);
            const float mu = muL[r], rs = rsL[r];
            short8 o;
            o[0] = (short)f2bf((t0.x - mu)*rs*g0.x + b0.x);
            o[1] = (short)f2bf((t0.y - mu)*rs*g0.y + b0.y);
            o[2] = (short)f2bf((t0.z - mu)*rs*g0.z + b0.z);
            o[3] = (short)f2bf((t0.w - mu)*rs*g0.w + b0.w);
            o[4] = (short)f2bf((t1.x - mu)*rs*g1.x + b1.x);
            o[5] = (short)f2bf((t1.y - mu)*rs*g1.y + b1.y);
            o[6] = (short)f2bf((t1.z - mu)*rs*g1.z + b1.z);
            o[7] = (short)f2bf((t1.w - mu)*rs*g1.w + b1.w);
            av[i] = o;
        }
        #pragma unroll
        for (int i = 0; i < 2; ++i)
            *(short8*)(As + ((w*2 + i)*8)*64 + lane*8) = av[i];
        __syncthreads();
        #pragma unroll
        for (int k32 = 0; k32 < 64; k32 += 32) {
            short8 af[2], bf[2];
            #pragma unroll
            for (int t = 0; t < 2; ++t) {
                const int ra  = 32*(w & 1) + 16*t + m15;
                const int sba = ((k32>>3) + q) ^ (ra & 7);
                af[t] = *(const short8*)(As + ra*64 + sba*8);
                const int rb  = 32*(w >> 1) + 16*t + m15;
                const int sbb = ((k32>>3) + q) ^ (rb & 7);
                bf[t] = *(const short8*)(Bs + rb*64 + sbb*8);
            }
            #pragma unroll
            for (int mt = 0; mt < 2; ++mt)
                #pragma unroll
                for (int nt = 0; nt < 2; ++nt)
                    acc[mt][nt] = __builtin_amdgcn_mfma_f32_16x16x32_bf16(
                        af[mt], bf[nt], acc[mt][nt], 0, 0, 0);
        }
    }
    const int wm = w & 1, wn = w >> 1;
    #pragma unroll
    for (int mt=0;mt<2;++mt)
        #pragma unroll
        for (int nt=0;nt<2;++nt){
            const int n = n0 + 32*wn + 16*nt + m15;
            const float bb = bcat[896 + n];
            #pragma unroll
            for (int reg=0;reg<4;++reg){
                const int m = row0 + 32*wm + 16*mt + q*4 + reg;
                out[(size_t)m*512 + n] = x[(size_t)m*512 + n] + acc[mt][nt][reg] + bb;
            }
        }
}

extern "C" void kernel_launch(void* const* d_in, const int* in_sizes, int n_in,
                              void* d_out, int out_size, void* d_ws, size_t ws_size,
                              hipStream_t stream) {
    const float* x    = (const float*)d_in[0];
    const float* Wk   = (const float*)d_in[1];
    const float* bk   = (const float*)d_in[2];
    const float* Wq   = (const float*)d_in[3];
    const float* bq   = (const float*)d_in[4];
    const float* Wv   = (const float*)d_in[5];
    const float* bv   = (const float*)d_in[6];
    const float* ln_g = (const float*)d_in[7];
    const float* ln_b = (const float*)d_in[8];
    const float* Wo   = (const float*)d_in[9];
    const float* bo   = (const float*)d_in[10];
    const float* set_w      = (const float*)d_in[11];
    const float* pos_phases = (const float*)d_in[12];
    const float* pos_weight = (const float*)d_in[13];
    const float* Wg1  = (const float*)d_in[14];
    const float* bg1  = (const float*)d_in[15];
    const float* Wg2  = (const float*)d_in[16];
    const float* bg2  = (const float*)d_in[17];
    float* out = (float*)d_out;

    // workspace: fp32 region, then bf16 region (~14 MB)
    float* ws   = (float*)d_ws;
    float* Yh   = ws;                                     // 2048*384
    float* T    = Yh + (size_t)2048*YH;                   // 2048*512 fp32
    float* bcat = T  + (size_t)2048*512;                  // 1408
    unsigned short* Wb  = (unsigned short*)(bcat + NW);   // 1408*512
    unsigned short* xb  = Wb  + (size_t)NW*512;           // 2048*512
    unsigned short* Vt  = xb  + (size_t)2048*512;         // 2*512*1024
    unsigned short* ab  = Vt  + (size_t)BB*512*1024;      // 2048*64
    unsigned short* Rb  = ab  + (size_t)2048*NCH;         // 2048*64
    unsigned short* aT  = Rb  + (size_t)2048*NCH;         // 2*64*1024

    k_prep<<<dim3(NW + 2048), 128, 0, stream>>>(
        Wv,Wg1,Wk,Wq,Wo, bv,bg1,bk,bq,bo, x, Wb, bcat, xb);
    kg1<<<dim3(2048/64, 14), 256, 0, stream>>>(xb, Wb, bcat, Vt, Yh);
    k_act<<<dim3(2048/8), 256, 0, stream>>>(
        Yh, Wg2, bg2, set_w, pos_phases, pos_weight, ab, Rb, aT);
    k_scan<<<dim3(8, BB, NCHUNK), 256, 0, stream>>>(ab, Rb, aT, Vt, T);
    kg2ln<<<dim3(2048/64, 512/64), 256, 0, stream>>>(
        T, Wb, bcat, ln_g, ln_b, x, out);
}